// Round 1
// baseline (1709.008 us; speedup 1.0000x reference)
//
#include <hip/hip_runtime.h>
#include <hip/hip_bf16.h>
#include <math.h>

typedef unsigned short u16;

#define Bz 64
#define Tt 4096
#define Cin 64
#define K1c 128
#define Hh 96
#define T2 1024
#define G4 384
#define NC 109

__device__ __forceinline__ float bf2f(u16 v) {
  union { unsigned int u; float f; } x; x.u = ((unsigned int)v) << 16; return x.f;
}
__device__ __forceinline__ u16 f2bf(float f) {
  union { unsigned int u; float f; } x; x.f = f;
  unsigned int u = x.u;
  unsigned int r = u + 0x7fff + ((u >> 16) & 1);
  return (u16)(r >> 16);
}

// ---------------- K0: weight transposes + BN folding ----------------
__global__ void k_prep(const float* __restrict__ w1, const float* __restrict__ cb1,
                       const float* __restrict__ g1, const float* __restrict__ b1,
                       const float* __restrict__ m1, const float* __restrict__ v1,
                       const float* __restrict__ w2, const float* __restrict__ cb2,
                       const float* __restrict__ g2, const float* __restrict__ b2,
                       const float* __restrict__ m2, const float* __restrict__ v2,
                       const float* __restrict__ wr, const float* __restrict__ cbr,
                       const float* __restrict__ gr, const float* __restrict__ br,
                       const float* __restrict__ mr, const float* __restrict__ vr,
                       const float* __restrict__ wx,
                       float* __restrict__ w1T, float* __restrict__ w2T,
                       float* __restrict__ wrT, float* __restrict__ wxT,
                       float* __restrict__ al1, float* __restrict__ be1,
                       float* __restrict__ al2, float* __restrict__ be2,
                       float* __restrict__ alr, float* __restrict__ ber)
{
  int tid = blockIdx.x * blockDim.x + threadIdx.x;
  int nth = gridDim.x * blockDim.x;
  // w1T[(i*7+k)*128 + o] = w1[o][i][k]
  for (int idx = tid; idx < 448 * 128; idx += nth) {
    int o = idx & 127, r = idx >> 7, i = r / 7, k = r % 7;
    w1T[idx] = w1[(o * 64 + i) * 7 + k];
  }
  // w2T[(i*3+k)*96 + o] = w2[o][i][k]
  for (int idx = tid; idx < 384 * 96; idx += nth) {
    int o = idx % 96, r = idx / 96, i = r / 3, k = r % 3;
    w2T[idx] = w2[(o * 128 + i) * 3 + k];
  }
  // wrT[i*96 + o] = wr[o][i]
  for (int idx = tid; idx < 128 * 96; idx += nth) {
    int o = idx % 96, i = idx / 96;
    wrT[idx] = wr[o * 128 + i];
  }
  // wxT[h*384 + g] = wx[g][h]
  for (int idx = tid; idx < 96 * 384; idx += nth) {
    int g = idx % 384, h = idx / 384;
    wxT[idx] = wx[g * 96 + h];
  }
  for (int o = tid; o < 128; o += nth) {
    float a = g1[o] / sqrtf(v1[o] + 1e-5f);
    al1[o] = a; be1[o] = b1[o] + (cb1[o] - m1[o]) * a;
  }
  for (int o = tid; o < 96; o += nth) {
    float a = g2[o] / sqrtf(v2[o] + 1e-5f);
    al2[o] = a; be2[o] = b2[o] + (cb2[o] - m2[o]) * a;
    float ar = gr[o] / sqrtf(vr[o] + 1e-5f);
    alr[o] = ar; ber[o] = br[o] + (cbr[o] - mr[o]) * ar;
  }
}

// ---------------- K1: conv1 (k=7,s=1,p=3) + bn1 + relu -> out1 bf16 [B][T][128] ----------------
__launch_bounds__(256)
__global__ void k_conv1(const float* __restrict__ x, const float* __restrict__ w1T,
                        const float* __restrict__ al1, const float* __restrict__ be1,
                        u16* __restrict__ out1)
{
  __shared__ __align__(16) float xsT[64 * 76];   // [i][row], rows 0..69 valid
  __shared__ __align__(16) float wbuf[56 * 128]; // K-slice of w1T
  int tid = threadIdx.x;
  int b = blockIdx.y;
  int t0 = blockIdx.x * 64;
  const float* xb = x + (size_t)b * Tt * Cin;
  for (int idx = tid; idx < 70 * 64; idx += 256) {
    int row = idx >> 6, col = idx & 63;
    int gt = t0 - 3 + row;
    float v = (gt >= 0 && gt < Tt) ? xb[(size_t)gt * 64 + col] : 0.f;
    xsT[col * 76 + row] = v;
  }
  int lane32 = tid & 31;
  int o4 = lane32 * 4;
  int trow = (tid >> 5) * 8;
  float acc[8][4];
#pragma unroll
  for (int m = 0; m < 8; m++)
#pragma unroll
    for (int j = 0; j < 4; j++) acc[m][j] = 0.f;

  for (int ib = 0; ib < 8; ib++) {
    __syncthreads();
    for (int idx = tid; idx < 56 * 128; idx += 256) wbuf[idx] = w1T[ib * 56 * 128 + idx];
    __syncthreads();
#pragma unroll
    for (int ii = 0; ii < 8; ii++) {
      int i = ib * 8 + ii;
      float ax[16];
      {
        const float4* xp = (const float4*)(xsT + i * 76 + trow);
        float4 q0 = xp[0], q1 = xp[1], q2 = xp[2], q3 = xp[3];
        ax[0] = q0.x; ax[1] = q0.y; ax[2] = q0.z; ax[3] = q0.w;
        ax[4] = q1.x; ax[5] = q1.y; ax[6] = q1.z; ax[7] = q1.w;
        ax[8] = q2.x; ax[9] = q2.y; ax[10] = q2.z; ax[11] = q2.w;
        ax[12] = q3.x; ax[13] = q3.y; ax[14] = q3.z; ax[15] = q3.w;
      }
#pragma unroll
      for (int k = 0; k < 7; k++) {
        float4 bw = ((const float4*)wbuf)[(ii * 7 + k) * 32 + lane32];
#pragma unroll
        for (int m = 0; m < 8; m++) {
          float a = ax[m + k];
          acc[m][0] += a * bw.x; acc[m][1] += a * bw.y;
          acc[m][2] += a * bw.z; acc[m][3] += a * bw.w;
        }
      }
    }
  }
  float4 A = *(const float4*)(al1 + o4);
  float4 Bt = *(const float4*)(be1 + o4);
  u16* ob = out1 + ((size_t)b * Tt + t0 + trow) * 128 + o4;
#pragma unroll
  for (int m = 0; m < 8; m++) {
    float v0 = fmaxf(acc[m][0] * A.x + Bt.x, 0.f);
    float v1 = fmaxf(acc[m][1] * A.y + Bt.y, 0.f);
    float v2 = fmaxf(acc[m][2] * A.z + Bt.z, 0.f);
    float v3 = fmaxf(acc[m][3] * A.w + Bt.w, 0.f);
    ushort4 s;
    s.x = f2bf(v0); s.y = f2bf(v1); s.z = f2bf(v2); s.w = f2bf(v3);
    *(ushort4*)(ob + (size_t)m * 128) = s;
  }
}

// ---------------- K2: conv2(k=3,s=4,p=1)+bn2+relu + res(k=1,s=4)+bnr, add -> seq f32 [B][1024][96] ----------------
__launch_bounds__(256)
__global__ void k_conv2(const u16* __restrict__ out1, const float* __restrict__ w2T,
                        const float* __restrict__ wrT,
                        const float* __restrict__ al2, const float* __restrict__ be2,
                        const float* __restrict__ alr, const float* __restrict__ ber,
                        float* __restrict__ seq)
{
  __shared__ __align__(16) u16 xs2[127 * 128];
  __shared__ float ws2[48 * 96];
  __shared__ float wsr[16 * 96];
  int tid = threadIdx.x;
  int b = blockIdx.y;
  int t20 = blockIdx.x * 32;
  int row0 = 4 * t20 - 1;
  const u16* ob = out1 + (size_t)b * Tt * 128;
  for (int idx4 = tid; idx4 < 127 * 32; idx4 += 256) {
    int row = idx4 >> 5, c4 = (idx4 & 31) * 4;
    int gr = row0 + row;
    ushort4 v;
    if (gr >= 0 && gr < Tt) v = *(const ushort4*)(ob + (size_t)gr * 128 + c4);
    else { v.x = 0; v.y = 0; v.z = 0; v.w = 0; }
    *(ushort4*)(xs2 + row * 128 + c4) = v;
  }
  int o3 = (tid & 31) * 3;
  int t4 = (tid >> 5) * 4;
  float acc[4][3], accr[4][3];
#pragma unroll
  for (int mt = 0; mt < 4; mt++)
#pragma unroll
    for (int j = 0; j < 3; j++) { acc[mt][j] = 0.f; accr[mt][j] = 0.f; }

  for (int ic = 0; ic < 8; ic++) {
    __syncthreads();
    int i0 = ic * 16;
    for (int idx = tid; idx < 48 * 96; idx += 256) ws2[idx] = w2T[i0 * 3 * 96 + idx];
    for (int idx = tid; idx < 16 * 96; idx += 256) wsr[idx] = wrT[i0 * 96 + idx];
    __syncthreads();
#pragma unroll
    for (int ii = 0; ii < 16; ii++) {
      int i = i0 + ii;
      float a[4][3];
#pragma unroll
      for (int mt = 0; mt < 4; mt++)
#pragma unroll
        for (int k = 0; k < 3; k++)
          a[mt][k] = bf2f(xs2[(4 * (t4 + mt) + k) * 128 + i]);
#pragma unroll
      for (int k = 0; k < 3; k++) {
        float w0 = ws2[(ii * 3 + k) * 96 + o3];
        float w1 = ws2[(ii * 3 + k) * 96 + o3 + 1];
        float w2v = ws2[(ii * 3 + k) * 96 + o3 + 2];
#pragma unroll
        for (int mt = 0; mt < 4; mt++) {
          acc[mt][0] += a[mt][k] * w0;
          acc[mt][1] += a[mt][k] * w1;
          acc[mt][2] += a[mt][k] * w2v;
        }
      }
      float r0 = wsr[ii * 96 + o3];
      float r1 = wsr[ii * 96 + o3 + 1];
      float r2 = wsr[ii * 96 + o3 + 2];
#pragma unroll
      for (int mt = 0; mt < 4; mt++) {
        accr[mt][0] += a[mt][1] * r0;
        accr[mt][1] += a[mt][1] * r1;
        accr[mt][2] += a[mt][1] * r2;
      }
    }
  }
  float A0 = al2[o3], A1 = al2[o3 + 1], A2 = al2[o3 + 2];
  float B0 = be2[o3], B1 = be2[o3 + 1], B2 = be2[o3 + 2];
  float Ar0 = alr[o3], Ar1 = alr[o3 + 1], Ar2 = alr[o3 + 2];
  float Br0 = ber[o3], Br1 = ber[o3 + 1], Br2 = ber[o3 + 2];
  float* sb = seq + ((size_t)b * T2 + t20 + t4) * 96 + o3;
#pragma unroll
  for (int mt = 0; mt < 4; mt++) {
    sb[(size_t)mt * 96 + 0] = fmaxf(acc[mt][0] * A0 + B0, 0.f) + accr[mt][0] * Ar0 + Br0;
    sb[(size_t)mt * 96 + 1] = fmaxf(acc[mt][1] * A1 + B1, 0.f) + accr[mt][1] * Ar1 + Br1;
    sb[(size_t)mt * 96 + 2] = fmaxf(acc[mt][2] * A2 + B2, 0.f) + accr[mt][2] * Ar2 + Br2;
  }
}

// ---------------- K3: pre = seq @ wx^T + bias -> [B][1024][384] f32 ----------------
__launch_bounds__(256)
__global__ void k_pre(const float* __restrict__ seq, const float* __restrict__ wxT,
                      const float* __restrict__ bias, float* __restrict__ pre)
{
  __shared__ float seqs[32 * 96];
  __shared__ __align__(16) float wxs[96 * 128];
  int tid = threadIdx.x;
  int b = blockIdx.z, nt = blockIdx.y, t20 = blockIdx.x * 32;
  int g0 = nt * 128;
  for (int idx = tid; idx < 32 * 96; idx += 256)
    seqs[idx] = seq[((size_t)b * T2 + t20) * 96 + idx];
  for (int idx = tid; idx < 96 * 128; idx += 256) {
    int h = idx >> 7, c = idx & 127;
    wxs[idx] = wxT[h * 384 + g0 + c];
  }
  __syncthreads();
  int lane32 = tid & 31, o4 = lane32 * 4, t4 = (tid >> 5) * 4;
  float acc[4][4];
#pragma unroll
  for (int mt = 0; mt < 4; mt++)
#pragma unroll
    for (int j = 0; j < 4; j++) acc[mt][j] = 0.f;
  for (int k = 0; k < 96; k++) {
    float4 bw = ((const float4*)wxs)[k * 32 + lane32];
    float a0 = seqs[(t4 + 0) * 96 + k];
    float a1 = seqs[(t4 + 1) * 96 + k];
    float a2 = seqs[(t4 + 2) * 96 + k];
    float a3 = seqs[(t4 + 3) * 96 + k];
    acc[0][0] += a0 * bw.x; acc[0][1] += a0 * bw.y; acc[0][2] += a0 * bw.z; acc[0][3] += a0 * bw.w;
    acc[1][0] += a1 * bw.x; acc[1][1] += a1 * bw.y; acc[1][2] += a1 * bw.z; acc[1][3] += a1 * bw.w;
    acc[2][0] += a2 * bw.x; acc[2][1] += a2 * bw.y; acc[2][2] += a2 * bw.z; acc[2][3] += a2 * bw.w;
    acc[3][0] += a3 * bw.x; acc[3][1] += a3 * bw.y; acc[3][2] += a3 * bw.z; acc[3][3] += a3 * bw.w;
  }
  float4 b4 = *(const float4*)(bias + g0 + o4);
  float* pb = pre + ((size_t)b * T2 + t20 + t4) * 384 + g0 + o4;
#pragma unroll
  for (int mt = 0; mt < 4; mt++) {
    float4 v;
    v.x = acc[mt][0] + b4.x; v.y = acc[mt][1] + b4.y;
    v.z = acc[mt][2] + b4.z; v.w = acc[mt][3] + b4.w;
    *(float4*)(pb + (size_t)mt * 384) = v;
  }
}

// ---------------- K4: sLSTM recurrence, one block per batch ----------------
__launch_bounds__(768)
__global__ void k_slstm(const float* __restrict__ pre, const float* __restrict__ wh,
                        float* __restrict__ hsum)
{
  __shared__ __align__(16) float hbuf[96];
  __shared__ float gbuf[384];
  int tid = threadIdx.x;
  int b = blockIdx.x;
  int g = tid >> 1, s = tid & 1;
  float w[48];
  const float* wrow = wh + g * 96 + s * 48;
#pragma unroll
  for (int q = 0; q < 12; q++) {
    float4 v = ((const float4*)wrow)[q];
    w[4 * q] = v.x; w[4 * q + 1] = v.y; w[4 * q + 2] = v.z; w[4 * q + 3] = v.w;
  }
  float c = 0.f, n = 0.f, m = 0.f, hs = 0.f;
  if (tid < 96) hbuf[tid] = 0.f;
  __syncthreads();
  const float* pb = pre + (size_t)b * T2 * G4;
  for (int t = 0; t < T2; t++) {
    float a0 = 0.f, a1 = 0.f, a2 = 0.f, a3 = 0.f;
    const float4* hb4 = (const float4*)hbuf + s * 12;
#pragma unroll
    for (int q = 0; q < 12; q++) {
      float4 hv = hb4[q];
      a0 += hv.x * w[4 * q]; a1 += hv.y * w[4 * q + 1];
      a2 += hv.z * w[4 * q + 2]; a3 += hv.w * w[4 * q + 3];
    }
    float acc = (a0 + a1) + (a2 + a3);
    acc += __shfl_xor(acc, 1, 64);
    float pxv = pb[(size_t)t * G4 + g];
    gbuf[g] = acc + pxv;  // both lanes of the pair write the same value
    __syncthreads();
    if (tid < 96) {
      float zp = gbuf[tid], ip = gbuf[96 + tid], fpv = gbuf[192 + tid], op = gbuf[288 + tid];
      float z = tanhf(zp);
      float o = 1.f / (1.f + expf(-op));
      float mn = fmaxf(fpv + m, ip);
      float iv = expf(ip - mn);
      float fv = expf(fpv + m - mn);
      c = fv * c + iv * z;
      n = fv * n + iv;
      m = mn;
      float h = o * (c / fmaxf(n, 1.f));
      hbuf[tid] = h;
      hs += h;
    }
    __syncthreads();
  }
  if (tid < 96) hsum[b * 96 + tid] = hs * (1.f / 1024.f);
}

// ---------------- K5: head: mean-pooled -> fc1+relu -> fc2 ----------------
__launch_bounds__(128)
__global__ void k_head(const float* __restrict__ hsum, const float* __restrict__ fc1w,
                       const float* __restrict__ fc1b, const float* __restrict__ fc2w,
                       const float* __restrict__ fc2b, float* __restrict__ out)
{
  __shared__ float p[96];
  __shared__ float z1[128];
  int tid = threadIdx.x, b = blockIdx.x;
  if (tid < 96) p[tid] = hsum[b * 96 + tid];
  __syncthreads();
  {
    float a = fc1b[tid];
    const float* wr = fc1w + tid * 96;
    for (int h = 0; h < 96; h++) a += p[h] * wr[h];
    z1[tid] = fmaxf(a, 0.f);
  }
  __syncthreads();
  if (tid < NC) {
    float a = fc2b[tid];
    const float* wr = fc2w + tid * 128;
    for (int j = 0; j < 128; j++) a += z1[j] * wr[j];
    out[b * NC + tid] = a;
  }
}

extern "C" void kernel_launch(void* const* d_in, const int* in_sizes, int n_in,
                              void* d_out, int out_size, void* d_ws, size_t ws_size,
                              hipStream_t stream)
{
  const float* x    = (const float*)d_in[0];
  const float* w1   = (const float*)d_in[1];
  const float* cb1  = (const float*)d_in[2];
  const float* g1   = (const float*)d_in[3];
  const float* b1   = (const float*)d_in[4];
  const float* m1   = (const float*)d_in[5];
  const float* v1   = (const float*)d_in[6];
  const float* w2   = (const float*)d_in[7];
  const float* cb2  = (const float*)d_in[8];
  const float* g2   = (const float*)d_in[9];
  const float* b2   = (const float*)d_in[10];
  const float* m2   = (const float*)d_in[11];
  const float* v2   = (const float*)d_in[12];
  const float* wr   = (const float*)d_in[13];
  const float* cbr  = (const float*)d_in[14];
  const float* gr   = (const float*)d_in[15];
  const float* br   = (const float*)d_in[16];
  const float* mr   = (const float*)d_in[17];
  const float* vr   = (const float*)d_in[18];
  const float* wx   = (const float*)d_in[19];
  const float* wh   = (const float*)d_in[20];
  const float* sbia = (const float*)d_in[21];
  const float* fc1w = (const float*)d_in[22];
  const float* fc1b = (const float*)d_in[23];
  const float* fc2w = (const float*)d_in[24];
  const float* fc2b = (const float*)d_in[25];

  char* ws = (char*)d_ws;
  size_t off = 0;
  auto alloc = [&](size_t bytes) -> void* {
    void* p = (void*)(ws + off);
    off = (off + bytes + 255) & ~((size_t)255);
    return p;
  };
  u16*   out1 = (u16*)  alloc((size_t)Bz * Tt * K1c * 2);   // 67.1 MB
  float* seq  = (float*)alloc((size_t)Bz * T2 * Hh * 4);    // 25.2 MB
  float* pre  = (float*)alloc((size_t)Bz * T2 * G4 * 4);    // 100.7 MB
  float* w1T  = (float*)alloc(448 * 128 * 4);
  float* w2T  = (float*)alloc(384 * 96 * 4);
  float* wrT  = (float*)alloc(128 * 96 * 4);
  float* wxT  = (float*)alloc(96 * 384 * 4);
  float* al1  = (float*)alloc(128 * 4);
  float* be1  = (float*)alloc(128 * 4);
  float* al2  = (float*)alloc(96 * 4);
  float* be2  = (float*)alloc(96 * 4);
  float* alr  = (float*)alloc(96 * 4);
  float* ber  = (float*)alloc(96 * 4);
  float* hsum = (float*)alloc((size_t)Bz * Hh * 4);
  (void)ws_size; (void)in_sizes; (void)n_in; (void)out_size;

  k_prep<<<dim3(224), dim3(256), 0, stream>>>(
      w1, cb1, g1, b1, m1, v1, w2, cb2, g2, b2, m2, v2,
      wr, cbr, gr, br, mr, vr, wx,
      w1T, w2T, wrT, wxT, al1, be1, al2, be2, alr, ber);

  k_conv1<<<dim3(Tt / 64, Bz), dim3(256), 0, stream>>>(x, w1T, al1, be1, out1);

  k_conv2<<<dim3(T2 / 32, Bz), dim3(256), 0, stream>>>(out1, w2T, wrT, al2, be2, alr, ber, seq);

  k_pre<<<dim3(T2 / 32, 3, Bz), dim3(256), 0, stream>>>(seq, wxT, sbia, pre);

  k_slstm<<<dim3(Bz), dim3(768), 0, stream>>>(pre, wh, hsum);

  k_head<<<dim3(Bz), dim3(128), 0, stream>>>(hsum, fc1w, fc1b, fc2w, fc2b, (float*)d_out);
}